// Round 11
// baseline (402.935 us; speedup 1.0000x reference)
//
#include <hip/hip_runtime.h>
#include <cstdint>
#include <cstddef>

// Problem constants
#define M_DIM 8192
#define N_DIM 4096
#define K_DIM 4096

#define BM 256
#define BN 256
// K-tile = 128 bytes of K per row; 2 K-tiles per iteration; 4096/256 = 16 iters.

using i32x4  = __attribute__((ext_vector_type(4))) int;
using i32x16 = __attribute__((ext_vector_type(16))) int;

__device__ __forceinline__ void async_load16(const void* g, void* l) {
    __builtin_amdgcn_global_load_lds(
        (const __attribute__((address_space(1))) void*)g,
        (__attribute__((address_space(3))) void*)l,
        16, 0, 0);
}

// Pack int32 values (range [-128,127]) to int8, both buffers in one launch.
__global__ __launch_bounds__(256) void pack_i8_kernel(const int4* __restrict__ xsrc,
                                                      int* __restrict__ xdst,
                                                      const int4* __restrict__ wsrc,
                                                      int* __restrict__ wdst,
                                                      int nxblocks) {
    const bool isw = (int)blockIdx.x >= nxblocks;
    const int4* src = isw ? wsrc : xsrc;
    int*       dst  = isw ? wdst : xdst;
    const long bb   = isw ? ((long)blockIdx.x - nxblocks) : (long)blockIdx.x;
    const long base = bb * 1024 + threadIdx.x;
#pragma unroll
    for (int j = 0; j < 4; ++j) {
        const long i = base + 256 * j;
        const int4 v = src[i];
        dst[i] = (v.x & 0xff) | ((v.y & 0xff) << 8) | ((v.z & 0xff) << 16) | (v.w << 24);
    }
}

// 256x256-tile 8-phase i8 GEMM, single barrier per phase (r10 schedule),
// now on mfma_i32_32x32x32_i8 (4404 vs 3944 TOPS µbench, half the MFMA
// instruction count, identical register/LDS footprint; fragment + C/D maps
// hardware-verified in r3). ds_read bank pattern under the (row&7)-chunk
// XOR layout: chunk = (2kb+l5)^l7 -> 8 touches/bank = b128 floor (conflict-
// free). Staging uses uniform SGPR base + 32-bit per-lane voffset; bf[1]
// loads hoisted post-barrier of P1/P5 (MFMA there uses only bf[0]).
// vmcnt(6) checkpoints at P4/P8 only; T1 XCD-chunked block swizzle.
// LDS map (128 KiB): A: buf*32768 + half*16384 + row*128; B: +65536.
__global__ __launch_bounds__(512, 2) void qgemm_i8_kernel(const int8_t* __restrict__ A,
                                                          const int8_t* __restrict__ B,
                                                          const int* __restrict__ bias,
                                                          const float* __restrict__ wscale,
                                                          int* __restrict__ C) {
    __shared__ int8_t LDS[131072];

    const int tid  = threadIdx.x;
    const int wave = tid >> 6;
    const int lane = tid & 63;
    const int wm = wave >> 2;   // 0..1
    const int wn = wave & 3;    // 0..3

    // T1: XCD-chunked swizzle. grid = (16,32) -> 512 blocks, 512%8==0.
    const int lin = (int)(blockIdx.y * 16 + blockIdx.x);
    const int swz = (lin & 7) * 64 + (lin >> 3);
    const int bm = swz >> 4;    // 0..31
    const int bn = swz & 15;    // 0..15

    const int8_t* Ab = A + (size_t)bm * BM * K_DIM;   // uniform (SGPR) base
    const int8_t* Bb = B + (size_t)bn * BN * K_DIM;   // uniform (SGPR) base

    // Staging: per ISSUE_HT a wave covers 16 rows x 128B (2 x global_load_lds).
    // Per-lane 32-bit voffset; row/chunk swizzle (l7^l8) pre-applied (rule 21).
    const int l8 = lane >> 3;
    const int l7 = lane & 7;
    const int voffS = (wave * 16 + l8) * K_DIM + ((l7 ^ l8) * 16);
    const int sdst = wave * 2048;

    // 32x32 fragment geometry. Lane: row/col = lane&31, k-half = lane>>5 (16B).
    // LDS chunk for (kb, l5) at row r: (2kb+l5)^(r&7); r&7 == lane&7.
    // byte = 16*(l5^(lane&1)) + 32*(kb^h2), h2 = (lane&7)>>1.
    const int l31 = lane & 31;
    const int l5  = lane >> 5;
    const int h2  = l7 >> 1;
    const int aoff = wm * 8192 + l31 * 128 + 16 * (l5 ^ (lane & 1));
    const int boff = 65536 + wn * 4096 + l31 * 128 + 16 * (l5 ^ (lane & 1));

    i32x16 acc[4][2] = {};   // [quadrant][mb] : 32x32 tiles, 128 regs total
    i32x4 af[2][4];          // A-half fragments [mb][kb] (held across phases)
    i32x4 bf[2][4];          // BOTH B-half fragments [nh][kb], held all K-tile

#define ISSUE_HT(MATB, REG, BUF, HH, T) do { \
    const int8_t* _b = (MATB) + (size_t)((HH) * 128) * K_DIM + (size_t)(T) * 128; \
    async_load16(_b + voffS, \
                 &LDS[(REG) + (BUF) * 32768 + (HH) * 16384 + sdst]); \
    async_load16(_b + 8 * K_DIM + voffS, \
                 &LDS[(REG) + (BUF) * 32768 + (HH) * 16384 + sdst + 1024]); \
} while (0)

#define LOAD_AF(BUF, MH) do { \
    _Pragma("unroll") \
    for (int mb = 0; mb < 2; ++mb) { \
        _Pragma("unroll") \
        for (int kb = 0; kb < 4; ++kb) \
            af[mb][kb] = *(const i32x4*)&LDS[aoff + (BUF) * 32768 + (MH) * 16384 \
                                             + mb * 4096 + ((kb ^ h2) * 32)]; \
    } \
} while (0)

#define LOAD_BF(BUF, NH) do { \
    _Pragma("unroll") \
    for (int kb = 0; kb < 4; ++kb) \
        bf[NH][kb] = *(const i32x4*)&LDS[boff + (BUF) * 32768 + (NH) * 16384 \
                                         + ((kb ^ h2) * 32)]; \
} while (0)

#define VM6 asm volatile("s_waitcnt vmcnt(6)" ::: "memory")
#define VM0 asm volatile("s_waitcnt vmcnt(0)" ::: "memory")

// One phase: pre-barrier ds_reads + staging issues + optional vmcnt checkpoint,
// ONE barrier, optional post-barrier ds_reads (next phase's conflict-free
// fragments, hidden under MFMA), then the 8-MFMA 32x32 quadrant cluster.
#define PHASE(LOADS, QD, NHB, ISSUES, CHK, POST) do { \
    LOADS; \
    ISSUES; \
    CHK; \
    __builtin_amdgcn_s_barrier(); \
    POST; \
    __builtin_amdgcn_s_setprio(1); \
    _Pragma("unroll") \
    for (int kb = 0; kb < 4; ++kb) { \
        acc[QD][0] = __builtin_amdgcn_mfma_i32_32x32x32_i8(af[0][kb], bf[NHB][kb], acc[QD][0], 0, 0, 0); \
        acc[QD][1] = __builtin_amdgcn_mfma_i32_32x32x32_i8(af[1][kb], bf[NHB][kb], acc[QD][1], 0, 0, 0); \
    } \
    __builtin_amdgcn_s_setprio(0); \
} while (0)

    // ---- prologue: tile0 fully + tile1 partial (A1h0, B1h0, B1h1).
    // A1h1(t1) is issued at P1 of iter 0. vmcnt(6) drains HT1-4 (all buf0),
    // covering P1's pre reads, P1's post bf[1] read, and P3's read.
    ISSUE_HT(Ab, 0,     0, 0, 0);   // #1 A0h0
    ISSUE_HT(Bb, 65536, 0, 0, 0);   // #2 B0h0
    ISSUE_HT(Bb, 65536, 0, 1, 0);   // #3 B0h1
    ISSUE_HT(Ab, 0,     0, 1, 0);   // #4 A0h1
    ISSUE_HT(Ab, 0,     1, 0, 1);   // #5 A1h0
    ISSUE_HT(Bb, 65536, 1, 0, 1);   // #6 B1h0
    ISSUE_HT(Bb, 65536, 1, 1, 1);   // #7 B1h1
    VM6;
    __builtin_amdgcn_s_barrier();

    // ---- main loop. Iter i: tiles U=2i (buf0, P1-4), V=2i+1 (buf1, P5-8).
    // Quadrants: P1=(0,0) P2=(0,1) P3=(1,1) P4=(1,0).
    // Overwrite ledger (single-barrier rule: issue >= last-read + 2); reads of
    // Bh1 hoisted one phase EARLIER (P1/P5 post-barrier) only widens margins.
    // Landing ledger (per-wave FIFO, 2 loads/HT): VM6@P4 drains prevP7+prevP8+P1
    // covering P5-P7 reads; VM6@P8 drains P3+P4+P5 covering next P1-P3 reads
    // (incl. P1's post bf[1] = Bh1 issued at P4). Last iter: VM0@P4.
    for (int i = 0; i < 16; ++i) {
        const int V = 2 * i + 1;
        const int W = 2 * i + 2;   // -> buf0
        const int X = 2 * i + 3;   // -> buf1
        const bool more = (i < 15);

        PHASE({ LOAD_AF(0, 0); LOAD_BF(0, 0); }, 0, 0,
              { ISSUE_HT(Ab, 0,     1, 1, V); }, {},
              { LOAD_BF(0, 1); });
        PHASE({}, 1, 1,
              {}, {}, {});
        PHASE({ LOAD_AF(0, 1); }, 2, 1,
              { if (more) { ISSUE_HT(Ab, 0, 0, 0, W); ISSUE_HT(Bb, 65536, 0, 0, W); } }, {}, {});
        PHASE({}, 3, 0,
              { if (more) ISSUE_HT(Bb, 65536, 0, 1, W); },
              { if (more) { VM6; } else { VM0; } }, {});
        PHASE({ LOAD_AF(1, 0); LOAD_BF(1, 0); }, 0, 0,
              { if (more) ISSUE_HT(Ab, 0,     0, 1, W); }, {},
              { LOAD_BF(1, 1); });
        PHASE({}, 1, 1,
              {}, {}, {});
        PHASE({ LOAD_AF(1, 1); }, 2, 1,
              { if (more) { ISSUE_HT(Ab, 0, 1, 0, X); ISSUE_HT(Bb, 65536, 1, 0, X); } }, {}, {});
        PHASE({}, 3, 0,
              { if (more) ISSUE_HT(Bb, 65536, 1, 1, X); },
              { if (more) { VM6; } }, {});
    }

#undef PHASE
#undef VM0
#undef VM6
#undef LOAD_BF
#undef LOAD_AF
#undef ISSUE_HT

    // ---- epilogue. 32x32 C/D layout (r3-verified): col = lane&31,
    // row = (reg&3) + 8*(reg>>2) + 4*(lane>>5).
    // Quad map: qd -> (mh, nh): 0=(0,0) 1=(0,1) 2=(1,1) 3=(1,0).
#pragma unroll
    for (int qd = 0; qd < 4; ++qd) {
        const int mh = qd >> 1;
        const int nh = (qd >> 1) ^ (qd & 1);
        const int col = bn * BN + nh * 128 + wn * 32 + l31;
        // match np ref arithmetic exactly: (0.05f * ws) / 0.1f, all f32
        float s = 0.05f * wscale[col];
        s = s / 0.1f;
        const float bz = (float)bias[col];
#pragma unroll
        for (int mb = 0; mb < 2; ++mb) {
            const int row0 = bm * BM + mh * 128 + wm * 64 + mb * 32 + 4 * l5;
#pragma unroll
            for (int r = 0; r < 16; ++r) {
                const int row = row0 + (r & 3) + 8 * (r >> 2);
                float v = ((float)acc[qd][mb][r] + bz) * s;
                v = rintf(v);                          // RTNE, matches np.round
                v = fminf(fmaxf(v, -128.0f), 127.0f);
                C[(size_t)row * N_DIM + col] = (int)v;
            }
        }
    }
}

extern "C" void kernel_launch(void* const* d_in, const int* in_sizes, int n_in,
                              void* d_out, int out_size, void* d_ws, size_t ws_size,
                              hipStream_t stream) {
    const int*   x32    = (const int*)d_in[0];     // int8 values promoted to int32
    const int*   w32    = (const int*)d_in[1];
    const int*   bias   = (const int*)d_in[2];
    const float* wscale = (const float*)d_in[3];
    int*         out    = (int*)d_out;

    int8_t* xp = (int8_t*)d_ws;                         // 32 MiB packed x
    int8_t* wp = xp + (size_t)M_DIM * K_DIM;            // 16 MiB packed w

    {
        const int nxblocks = (int)((long)M_DIM * K_DIM / 4 / 1024);   // 8192
        const int nwblocks = (int)((long)N_DIM * K_DIM / 4 / 1024);   // 4096
        pack_i8_kernel<<<nxblocks + nwblocks, 256, 0, stream>>>(
            (const int4*)x32, (int*)xp, (const int4*)w32, (int*)wp, nxblocks);
    }

    dim3 grid(N_DIM / BN, M_DIM / BM);   // (16, 32)
    qgemm_i8_kernel<<<grid, 512, 0, stream>>>(xp, wp, bias, wscale, out);
}

// Round 12
// 384.660 us; speedup vs baseline: 1.0475x; 1.0475x over previous
//
#include <hip/hip_runtime.h>
#include <cstdint>
#include <cstddef>

// Problem constants
#define M_DIM 8192
#define N_DIM 4096
#define K_DIM 4096

#define BM 256
#define BN 256
// K-tile = 128 bytes of K per row; 2 K-tiles per iteration; 4096/256 = 16 iters.

using i32x4 = __attribute__((ext_vector_type(4))) int;

__device__ __forceinline__ void async_load16(const void* g, void* l) {
    __builtin_amdgcn_global_load_lds(
        (const __attribute__((address_space(1))) void*)g,
        (__attribute__((address_space(3))) void*)l,
        16, 0, 0);
}

// Pack int32 values (range [-128,127]) to int8, both buffers in one launch.
// BOTH sides 16B/lane coalesced via an in-LDS transpose:
//   load 4x int4 (coalesced), pack each to 1 dword, stage sm[256j + t]
//   (stride-1 write, conflict-free), barrier, read int4 at sm[4t..4t+3]
//   (contiguous b128), store one int4 (coalesced).
// Blocks [0, nxblocks) cover x; the rest cover w. 1024 int4s in / 256 out per block.
__global__ __launch_bounds__(256) void pack_i8_kernel(const int4* __restrict__ xsrc,
                                                      int4* __restrict__ xdst,
                                                      const int4* __restrict__ wsrc,
                                                      int4* __restrict__ wdst,
                                                      int nxblocks) {
    __shared__ int sm[1024];
    const bool isw = (int)blockIdx.x >= nxblocks;
    const int4* src = isw ? wsrc : xsrc;
    int4*      dst  = isw ? wdst : xdst;
    const long bb   = isw ? ((long)blockIdx.x - nxblocks) : (long)blockIdx.x;
    const int  t    = threadIdx.x;
    const long base = bb * 1024 + t;
#pragma unroll
    for (int j = 0; j < 4; ++j) {
        const int4 v = src[base + 256 * j];
        sm[256 * j + t] = (v.x & 0xff) | ((v.y & 0xff) << 8) | ((v.z & 0xff) << 16) | (v.w << 24);
    }
    __syncthreads();
    dst[bb * 256 + t] = *(const int4*)&sm[4 * t];
}

// 256x256-tile 8-phase i8 GEMM, single barrier per phase (r10 structure,
// measured best: ~128 us, MfmaUtil 47%, 0 bank conflicts). 16x16x64 MFMA.
// A wave finishing MFMA(p) proceeds straight into LOADS/ISSUES(p+1); the only
// sync point is the barrier before each MFMA cluster. Overwrite safety under
// one barrier requires issue-phase >= last-read-phase + 2. Staging schedule:
// P1:A1h1(V) P3:A0h0,B0h0(W) P4:B0h1(W) P5:A0h1(W) P7:A1h0,B1h0(X) P8:B1h1(X).
// vmcnt(6) checkpoints at P4/P8 only (FIFO ledger: P4 drains prevP7/prevP8/P1
// covering P5-P7 reads; P8 drains P3/P4/P5 covering next P1-P3 reads).
// Gray-code quadrants hold A-half + both B-halves in regs
// (24 ds_read_b128/wave/K-tile). T1 XCD-chunked block swizzle.
// LDS map (128 KiB): A: buf*32768 + half*16384 + row*128; B: +65536.
// 16B chunks XOR-swizzled by (row&7) via pre-swizzled global source (rule 21).
__global__ __launch_bounds__(512, 2) void qgemm_i8_kernel(const int8_t* __restrict__ A,
                                                          const int8_t* __restrict__ B,
                                                          const int* __restrict__ bias,
                                                          const float* __restrict__ wscale,
                                                          int* __restrict__ C) {
    __shared__ int8_t LDS[131072];

    const int tid  = threadIdx.x;
    const int wave = tid >> 6;
    const int lane = tid & 63;
    const int wm = wave >> 2;   // 0..1
    const int wn = wave & 3;    // 0..3

    // T1: XCD-chunked swizzle. grid = (16,32) -> 512 blocks, 512%8==0.
    // lin%8 = XCD (dispatch round-robin); XCD r covers bm in [4r, 4r+4) x all bn.
    const int lin = (int)(blockIdx.y * 16 + blockIdx.x);
    const int swz = (lin & 7) * 64 + (lin >> 3);
    const int bm = swz >> 4;    // 0..31
    const int bn = swz & 15;    // 0..15

    const int8_t* Ab = A + (size_t)bm * BM * K_DIM;
    const int8_t* Bb = B + (size_t)bn * BN * K_DIM;

    // Staging: per ISSUE_HT a wave covers 16 rows x 128B (2 x global_load_lds).
    // Lane l -> row +(l>>3), source chunk (l&7)^(l>>3) (pre-swizzled global).
    const int l8 = lane >> 3;
    const int l7 = lane & 7;
    const int8_t* Ag = Ab + (size_t)(wave * 16 + l8) * K_DIM + ((l7 ^ l8) * 16);
    const int8_t* Bg = Bb + (size_t)(wave * 16 + l8) * K_DIM + ((l7 ^ l8) * 16);
    const int sdst = wave * 2048;

    // Fragment ds_read bases. A row = mh*128 + wm*64 + mi*16 + (lane&15);
    // chunk = (kk*4 + (lane>>4)) ^ (row&7); row&7 == lane&7. kk=1 addr = kk=0 ^ 64.
    const int l15 = lane & 15;
    const int qh  = lane >> 4;
    const int a_off0 = wm * 8192 + l15 * 128 + ((qh ^ l7) * 16);
    const int a_off1 = a_off0 ^ 64;
    const int b_off0 = 65536 + wn * 4096 + l15 * 128 + ((qh ^ l7) * 16);
    const int b_off1 = b_off0 ^ 64;

    i32x4 acc[4][4][2] = {};   // [quadrant][mi][ni]
    i32x4 af[4][2];            // current A-half fragments (held across phases)
    i32x4 bf[2][2][2];         // BOTH B-half fragments [nh][ni][kk], held all K-tile

#define ISSUE_HT(GB, REG, BUF, HH, T) do { \
    async_load16((GB) + (size_t)((HH) * 128)     * K_DIM + (size_t)(T) * 128, \
                 &LDS[(REG) + (BUF) * 32768 + (HH) * 16384 + sdst]); \
    async_load16((GB) + (size_t)((HH) * 128 + 8) * K_DIM + (size_t)(T) * 128, \
                 &LDS[(REG) + (BUF) * 32768 + (HH) * 16384 + sdst + 1024]); \
} while (0)

#define LOAD_AF(BUF, MH) do { \
    _Pragma("unroll") \
    for (int mi = 0; mi < 4; ++mi) { \
        af[mi][0] = *(const i32x4*)&LDS[a_off0 + (BUF) * 32768 + (MH) * 16384 + mi * 2048]; \
        af[mi][1] = *(const i32x4*)&LDS[a_off1 + (BUF) * 32768 + (MH) * 16384 + mi * 2048]; \
    } \
} while (0)

#define LOAD_BF(BUF, NH) do { \
    _Pragma("unroll") \
    for (int ni = 0; ni < 2; ++ni) { \
        bf[NH][ni][0] = *(const i32x4*)&LDS[b_off0 + (BUF) * 32768 + (NH) * 16384 + ni * 2048]; \
        bf[NH][ni][1] = *(const i32x4*)&LDS[b_off1 + (BUF) * 32768 + (NH) * 16384 + ni * 2048]; \
    } \
} while (0)

#define VM6 asm volatile("s_waitcnt vmcnt(6)" ::: "memory")
#define VM0 asm volatile("s_waitcnt vmcnt(0)" ::: "memory")

// One phase: ds_reads + staging issues + optional vmcnt checkpoint, ONE
// barrier, then the 16-MFMA quadrant cluster. No closing barrier: the wave
// rolls straight into the next phase's loads, overlapping other waves' MFMA.
#define PHASE(LOADS, QD, NHB, ISSUES, CHK) do { \
    LOADS; \
    ISSUES; \
    CHK; \
    __builtin_amdgcn_s_barrier(); \
    __builtin_amdgcn_s_setprio(1); \
    _Pragma("unroll") \
    for (int mi = 0; mi < 4; ++mi) { \
        _Pragma("unroll") \
        for (int ni = 0; ni < 2; ++ni) { \
            acc[QD][mi][ni] = __builtin_amdgcn_mfma_i32_16x16x64_i8(af[mi][0], bf[NHB][ni][0], acc[QD][mi][ni], 0, 0, 0); \
            acc[QD][mi][ni] = __builtin_amdgcn_mfma_i32_16x16x64_i8(af[mi][1], bf[NHB][ni][1], acc[QD][mi][ni], 0, 0, 0); \
        } \
    } \
    __builtin_amdgcn_s_setprio(0); \
} while (0)

    // ---- prologue: tile0 fully + tile1 partial (A1h0, B1h0, B1h1).
    // A1h1(t1) is issued at P1 of iter 0. vmcnt(6) drains HT1-4 (all buf0),
    // covering P1-P3 reads.
    ISSUE_HT(Ag, 0,     0, 0, 0);   // #1 A0h0
    ISSUE_HT(Bg, 65536, 0, 0, 0);   // #2 B0h0
    ISSUE_HT(Bg, 65536, 0, 1, 0);   // #3 B0h1
    ISSUE_HT(Ag, 0,     0, 1, 0);   // #4 A0h1
    ISSUE_HT(Ag, 0,     1, 0, 1);   // #5 A1h0
    ISSUE_HT(Bg, 65536, 1, 0, 1);   // #6 B1h0
    ISSUE_HT(Bg, 65536, 1, 1, 1);   // #7 B1h1
    VM6;
    __builtin_amdgcn_s_barrier();

    // ---- main loop. Iter i: tiles U=2i (buf0, P1-4), V=2i+1 (buf1, P5-8).
    // Quadrants: P1=(0,0) P2=(0,1) P3=(1,1) P4=(1,0).
    // Overwrite ledger (single-barrier rule: issue >= last-read + 2):
    //   buf0 Ah0/Bh0 read P1 -> issued P3; Bh1 read P2 -> P4; Ah1 read P3 -> P5
    //   buf1 Ah0/Bh0 read P5 -> issued P7; Bh1 read P6 -> P8; Ah1 read P7 -> next P1
    // Landing ledger: VM6@P4 drains prevP7+prevP8+P1 (covers P5-P7 reads);
    //   VM6@P8 drains P3+P4+P5 (covers next P1-P3 reads). Last iter: VM0@P4.
    for (int i = 0; i < 16; ++i) {
        const int V = 2 * i + 1;
        const int W = 2 * i + 2;   // -> buf0
        const int X = 2 * i + 3;   // -> buf1
        const bool more = (i < 15);

        PHASE({ LOAD_AF(0, 0); LOAD_BF(0, 0); }, 0, 0,
              { ISSUE_HT(Ag, 0,     1, 1, V); }, {});
        PHASE({ LOAD_BF(0, 1); }, 1, 1,
              {}, {});
        PHASE({ LOAD_AF(0, 1); }, 2, 1,
              { if (more) { ISSUE_HT(Ag, 0, 0, 0, W); ISSUE_HT(Bg, 65536, 0, 0, W); } }, {});
        PHASE({}, 3, 0,
              { if (more) ISSUE_HT(Bg, 65536, 0, 1, W); },
              { if (more) { VM6; } else { VM0; } });
        PHASE({ LOAD_AF(1, 0); LOAD_BF(1, 0); }, 0, 0,
              { if (more) ISSUE_HT(Ag, 0,     0, 1, W); }, {});
        PHASE({ LOAD_BF(1, 1); }, 1, 1,
              {}, {});
        PHASE({ LOAD_AF(1, 1); }, 2, 1,
              { if (more) { ISSUE_HT(Ag, 0, 1, 0, X); ISSUE_HT(Bg, 65536, 1, 0, X); } }, {});
        PHASE({}, 3, 0,
              { if (more) ISSUE_HT(Bg, 65536, 1, 1, X); },
              { if (more) { VM6; } });
    }

#undef PHASE
#undef VM0
#undef VM6
#undef LOAD_BF
#undef LOAD_AF
#undef ISSUE_HT

    // ---- epilogue. C/D layout (verified): col = lane&15, row = (lane>>4)*4 + reg.
    // Quad map: qd -> (mh, nh): 0=(0,0) 1=(0,1) 2=(1,1) 3=(1,0).
    const int col16 = lane & 15;
    const int rquad = (lane >> 4) * 4;
#pragma unroll
    for (int qd = 0; qd < 4; ++qd) {
        const int mh = qd >> 1;
        const int nh = (qd >> 1) ^ (qd & 1);
#pragma unroll
        for (int ni = 0; ni < 2; ++ni) {
            const int col = bn * BN + nh * 128 + wn * 32 + ni * 16 + col16;
            // match np ref arithmetic exactly: (0.05f * ws) / 0.1f, all f32
            float s = 0.05f * wscale[col];
            s = s / 0.1f;
            const float bz = (float)bias[col];
#pragma unroll
            for (int mi = 0; mi < 4; ++mi) {
                const int row0 = bm * BM + mh * 128 + wm * 64 + mi * 16 + rquad;
#pragma unroll
                for (int r = 0; r < 4; ++r) {
                    float v = ((float)acc[qd][mi][ni][r] + bz) * s;
                    v = rintf(v);                          // RTNE, matches np.round
                    v = fminf(fmaxf(v, -128.0f), 127.0f);
                    C[(size_t)(row0 + r) * N_DIM + col] = (int)v;
                }
            }
        }
    }
}

extern "C" void kernel_launch(void* const* d_in, const int* in_sizes, int n_in,
                              void* d_out, int out_size, void* d_ws, size_t ws_size,
                              hipStream_t stream) {
    const int*   x32    = (const int*)d_in[0];     // int8 values promoted to int32
    const int*   w32    = (const int*)d_in[1];
    const int*   bias   = (const int*)d_in[2];
    const float* wscale = (const float*)d_in[3];
    int*         out    = (int*)d_out;

    int8_t* xp = (int8_t*)d_ws;                         // 32 MiB packed x
    int8_t* wp = xp + (size_t)M_DIM * K_DIM;            // 16 MiB packed w

    {
        const int nxblocks = (int)((long)M_DIM * K_DIM / 4 / 1024);   // 8192
        const int nwblocks = (int)((long)N_DIM * K_DIM / 4 / 1024);   // 4096
        pack_i8_kernel<<<nxblocks + nwblocks, 256, 0, stream>>>(
            (const int4*)x32, (int4*)xp, (const int4*)w32, (int4*)wp, nxblocks);
    }

    dim3 grid(N_DIM / BN, M_DIM / BM);   // (16, 32)
    qgemm_i8_kernel<<<grid, 512, 0, stream>>>(xp, wp, bias, wscale, out);
}